// Round 6
// baseline (139.747 us; speedup 1.0000x reference)
//
#include <hip/hip_runtime.h>

// BatchTopK: relu(x), keep global top (k*1024) of 1024*24576 fp32, zero rest.
// Exact radix-select on positive-fp32 bit patterns + index-ordered tie-break.
//
// R6: split R5's fused k_main (66us, 2.4TB/s, VGPR=16 -> serialized loads)
// into two single-purpose streaming kernels:
//   k_fill: pure NT zero-fill of out (harness fill kernel proves 7TB/s)
//   k_read: pure x read + rare candidate compaction
// Selection pipeline unchanged.

#define N_ELEM   25165824            // 1024 * 24576
#define NV       (N_ELEM / 4)        // float4 count
#define HIST_SIZE 4096               // top-12-bit buckets
#define HREP     8                   // hist replicas
#define SREP     32                  // sample blocks / private replicas
#define NS       (NV / 64)           // sampled float4 count (1/64)
#define LCAP     1024                // per-block LDS candidate buffer
#define LCAP2    1024
#define TIE_CAP  4096
#define CAND2_CAP 262144
#define CAND_CAP  16777216

typedef float f32x4 __attribute__((ext_vector_type(4)));

// ws layout (uint32 words):
#define H_OFF     0                  // 8 x 4096 main hist (counts bits >= F)
#define H2_OFF    32768              // 8 x 4096 level-2 hist (bits[19:8] in b12)
#define HS_OFF    65536              // 32 x 4096 private sample hists
#define META_OFF  196608             // 16 words
#define CAND2_OFF 196624             // cutoff-bucket candidates, uint2
#define CAND_OFF  720912             // all candidates >= F, uint2 {bits, idx}
// meta: [0]=cand cnt [1]=b12 [2]=c_above [3]=fail [4]=F [5]=keepall
//       [6]=tau [7]=cand2 cnt [8]=cand cnt snapshot (pre-fallback)

// K0 (2048 blocks): pure nontemporal zero-fill of out. NV == 2048*256*12.
__global__ void k_fill(float4* __restrict__ out) {
    const f32x4 z = {0.f, 0.f, 0.f, 0.f};
    int tid = blockIdx.x * 256 + threadIdx.x;
    const int stride = 2048 * 256;
    #pragma unroll
    for (int j = 0; j < 12; ++j)
        __builtin_nontemporal_store(z, (f32x4*)&out[tid + j * stride]);
}

// K1 (32 blocks): zero hist+h2+meta; 1/64 sample -> private replica.
__global__ void k_sample(const float4* __restrict__ x, unsigned* __restrict__ ws) {
    __shared__ unsigned lh[HIST_SIZE];
    for (int i = threadIdx.x; i < HIST_SIZE; i += blockDim.x) lh[i] = 0u;
    int gid = blockIdx.x * blockDim.x + threadIdx.x;
    for (int i = gid; i < HS_OFF; i += SREP * 256) ws[i] = 0u;   // zero hist + h2
    if (gid < 16) ws[META_OFF + gid] = 0u;
    __syncthreads();
    for (int s = gid; s < NS; s += SREP * 256) {
        int c = s >> 6, l = s & 63;            // first 64 f4 of each 4096-f4 chunk
        float4 v = x[c * 4096 + l];
        if (v.x > 0.0f) atomicAdd(&lh[__float_as_uint(v.x) >> 20], 1u);
        if (v.y > 0.0f) atomicAdd(&lh[__float_as_uint(v.y) >> 20], 1u);
        if (v.z > 0.0f) atomicAdd(&lh[__float_as_uint(v.z) >> 20], 1u);
        if (v.w > 0.0f) atomicAdd(&lh[__float_as_uint(v.w) >> 20], 1u);
    }
    __syncthreads();
    unsigned* hs = ws + HS_OFF + blockIdx.x * HIST_SIZE;
    for (int i = threadIdx.x; i < HIST_SIZE; i += blockDim.x) hs[i] = lh[i];
}

// K2 (1 block): F = highest bucket with sampled suffix >= nk/8 (full ~ 8*nk).
__global__ void k_pick(unsigned* __restrict__ ws, const int* __restrict__ kptr) {
    __shared__ unsigned h[HIST_SIZE];
    __shared__ unsigned ps[1024];
    __shared__ unsigned F_sh;
    int t = threadIdx.x;
    if (t == 0) F_sh = 1u;
    unsigned nk = (unsigned)(*kptr) * 1024u;
    unsigned thr = nk / 8u; if (thr < 1u) thr = 1u;
    for (int i = t; i < HIST_SIZE; i += 1024) {
        unsigned s = 0u;
        #pragma unroll
        for (int r = 0; r < SREP; ++r) s += ws[HS_OFF + r * HIST_SIZE + i];
        h[i] = s;
    }
    __syncthreads();
    unsigned p = h[t*4] + h[t*4+1] + h[t*4+2] + h[t*4+3];
    ps[t] = p;
    __syncthreads();
    for (int st = 1; st < 1024; st <<= 1) {
        unsigned v = (t + st < 1024) ? ps[t + st] : 0u;
        __syncthreads();
        ps[t] += v;
        __syncthreads();
    }
    unsigned S = (t < 1023) ? ps[t + 1] : 0u;
    for (int j = 3; j >= 0; --j) {
        int b = t * 4 + j;
        unsigned Sb = S + h[b];
        if (Sb >= thr && S < thr) F_sh = ((unsigned)b) << 20;
        S = Sb;
    }
    __syncthreads();
    if (t == 0) ws[META_OFF + 4] = F_sh;
}

__device__ __forceinline__ void cand_push(unsigned b, unsigned idx,
                                          unsigned* lcnt, uint2* lc,
                                          unsigned* gcnt, uint2* cand, unsigned cap) {
    unsigned p = atomicAdd(lcnt, 1u);
    if (p < LCAP) lc[p] = make_uint2(b, idx);
    else { unsigned q = atomicAdd(gcnt, 1u); if (q < cap) cand[q] = make_uint2(b, idx); }
}

// K3 (2048 blocks x 256): pure x read + compact candidates >= F.
__global__ void k_read(const float4* __restrict__ x, unsigned* __restrict__ ws,
                       uint2* __restrict__ cand, unsigned cap) {
    __shared__ uint2 lc[LCAP];
    __shared__ unsigned lcnt, gbase;
    if (threadIdx.x == 0) lcnt = 0u;
    __syncthreads();
    unsigned* meta = ws + META_OFF;
    unsigned F = meta[4];
    unsigned* gcnt = &meta[0];
    int tid = blockIdx.x * 256 + threadIdx.x;
    const int stride = 2048 * 256;
    #pragma unroll
    for (int j = 0; j < 12; j += 4) {
        int i0 = tid + (j + 0) * stride;
        int i1 = tid + (j + 1) * stride;
        int i2 = tid + (j + 2) * stride;
        int i3 = tid + (j + 3) * stride;
        float4 v0 = x[i0];
        float4 v1 = x[i1];
        float4 v2 = x[i2];
        float4 v3 = x[i3];
        #pragma unroll
        for (int q = 0; q < 4; ++q) {
            float4 v = (q == 0) ? v0 : (q == 1) ? v1 : (q == 2) ? v2 : v3;
            int ii = (q == 0) ? i0 : (q == 1) ? i1 : (q == 2) ? i2 : i3;
            unsigned base = (unsigned)ii * 4u;
            unsigned b;
            b = __float_as_uint(fmaxf(v.x, 0.f)); if (b >= F) cand_push(b, base + 0u, &lcnt, lc, gcnt, cand, cap);
            b = __float_as_uint(fmaxf(v.y, 0.f)); if (b >= F) cand_push(b, base + 1u, &lcnt, lc, gcnt, cand, cap);
            b = __float_as_uint(fmaxf(v.z, 0.f)); if (b >= F) cand_push(b, base + 2u, &lcnt, lc, gcnt, cand, cap);
            b = __float_as_uint(fmaxf(v.w, 0.f)); if (b >= F) cand_push(b, base + 3u, &lcnt, lc, gcnt, cand, cap);
        }
    }
    __syncthreads();
    unsigned n = lcnt < LCAP ? lcnt : LCAP;
    if (threadIdx.x == 0 && n) gbase = atomicAdd(gcnt, n);
    __syncthreads();
    for (unsigned e = threadIdx.x; e < n; e += blockDim.x) {
        unsigned q = gbase + e;
        if (q < cap) cand[q] = lc[e];
    }
}

// K5 (guarded on fail): complement pass (0 < bits < F) appends to cand list.
__global__ void k_read_fb(const float4* __restrict__ x, unsigned* __restrict__ ws,
                          uint2* __restrict__ cand, unsigned cap) {
    unsigned* meta = ws + META_OFF;
    if (meta[3] == 0u) return;
    __shared__ uint2 lc[LCAP];
    __shared__ unsigned lcnt, gbase;
    if (threadIdx.x == 0) lcnt = 0u;
    __syncthreads();
    unsigned F = meta[4];
    unsigned* gcnt = &meta[0];
    int stride = gridDim.x * blockDim.x;
    for (int i = blockIdx.x * blockDim.x + threadIdx.x; i < NV; i += stride) {
        float4 v = x[i];
        unsigned base = (unsigned)i * 4u;
        unsigned b;
        b = __float_as_uint(fmaxf(v.x, 0.f)); if (b >= 1u && b < F) cand_push(b, base + 0u, &lcnt, lc, gcnt, cand, cap);
        b = __float_as_uint(fmaxf(v.y, 0.f)); if (b >= 1u && b < F) cand_push(b, base + 1u, &lcnt, lc, gcnt, cand, cap);
        b = __float_as_uint(fmaxf(v.z, 0.f)); if (b >= 1u && b < F) cand_push(b, base + 2u, &lcnt, lc, gcnt, cand, cap);
        b = __float_as_uint(fmaxf(v.w, 0.f)); if (b >= 1u && b < F) cand_push(b, base + 3u, &lcnt, lc, gcnt, cand, cap);
    }
    __syncthreads();
    unsigned n = lcnt < LCAP ? lcnt : LCAP;
    if (threadIdx.x == 0 && n) gbase = atomicAdd(gcnt, n);
    __syncthreads();
    for (unsigned e = threadIdx.x; e < n; e += blockDim.x) {
        unsigned q = gbase + e;
        if (q < cap) cand[q] = lc[e];
    }
}

// K4 (256 blocks): build top-12-bit histogram replicas from cand[lo..hi).
// is_fb==0: [0, cnt). is_fb==1 (guarded): [snapshot, cnt) — appended range only.
__global__ void k_histc(unsigned* __restrict__ ws, const uint2* __restrict__ cand,
                        unsigned cap, int is_fb) {
    unsigned* meta = ws + META_OFF;
    if (is_fb && meta[3] == 0u) return;
    __shared__ unsigned lh[HIST_SIZE];
    for (int i = threadIdx.x; i < HIST_SIZE; i += blockDim.x) lh[i] = 0u;
    __syncthreads();
    unsigned lo = is_fb ? meta[8] : 0u;
    unsigned hi = meta[0];
    if (hi > cap) hi = cap;
    if (lo > hi) lo = hi;
    unsigned stride = gridDim.x * blockDim.x;
    for (unsigned i = lo + blockIdx.x * blockDim.x + threadIdx.x; i < hi; i += stride)
        atomicAdd(&lh[cand[i].x >> 20], 1u);
    __syncthreads();
    unsigned* gh = ws + H_OFF + (blockIdx.x & (HREP - 1)) * HIST_SIZE;
    for (int i = threadIdx.x; i < HIST_SIZE; i += blockDim.x)
        if (lh[i]) atomicAdd(&gh[i], lh[i]);
}

// K6/K8 (1 block): suffix-scan replica-summed hist -> b12, c_above | fail | keepall.
__global__ void k_scan(unsigned* __restrict__ ws, const int* __restrict__ kptr, int is_fb) {
    unsigned* meta = ws + META_OFF;
    if (is_fb && meta[3] == 0u) return;
    __shared__ unsigned h[HIST_SIZE];
    __shared__ unsigned ps[1024];
    int t = threadIdx.x;
    unsigned nk = (unsigned)(*kptr) * 1024u;
    for (int i = t; i < HIST_SIZE; i += 1024) {
        unsigned s = 0u;
        #pragma unroll
        for (int r = 0; r < HREP; ++r) s += ws[H_OFF + r * HIST_SIZE + i];
        h[i] = s;
    }
    __syncthreads();
    unsigned p = h[t*4] + h[t*4+1] + h[t*4+2] + h[t*4+3];
    ps[t] = p;
    __syncthreads();
    for (int st = 1; st < 1024; st <<= 1) {
        unsigned v = (t + st < 1024) ? ps[t + st] : 0u;
        __syncthreads();
        ps[t] += v;
        __syncthreads();
    }
    unsigned total = ps[0];
    if (total < nk) {
        if (t == 0) {
            if (!is_fb) { meta[3] = 1u; meta[8] = meta[0]; }   // snapshot count
            else meta[5] = 1u;                                  // keep all positives
        }
        return;
    }
    unsigned S = (t < 1023) ? ps[t + 1] : 0u;
    for (int j = 3; j >= 0; --j) {
        int b = t * 4 + j;
        unsigned Sb = S + h[b];
        if (Sb >= nk && S < nk) { meta[1] = (unsigned)b; meta[2] = S; }
        S = Sb;
    }
}

// K9 (256 blocks): extract cutoff-bucket cands -> cand2, level-2 hist replicas.
__global__ void k_filter(unsigned* __restrict__ ws, const uint2* __restrict__ cand,
                         uint2* __restrict__ cand2, unsigned cap) {
    unsigned* meta = ws + META_OFF;
    if (meta[5]) return;
    __shared__ uint2 lc[LCAP2];
    __shared__ unsigned lcnt, gbase;
    if (threadIdx.x == 0) lcnt = 0u;
    __syncthreads();
    unsigned ncand = meta[0]; if (ncand > cap) ncand = cap;
    unsigned b12 = meta[1];
    unsigned* h2 = ws + H2_OFF + (blockIdx.x & (HREP - 1)) * HIST_SIZE;
    unsigned* cnt2 = &meta[7];
    unsigned stride = gridDim.x * blockDim.x;
    for (unsigned i = blockIdx.x * blockDim.x + threadIdx.x; i < ncand; i += stride) {
        uint2 c = cand[i];
        if ((c.x >> 20) == b12) {
            atomicAdd(&h2[(c.x >> 8) & 0xFFFu], 1u);
            unsigned p = atomicAdd(&lcnt, 1u);
            if (p < LCAP2) lc[p] = c;
            else { unsigned q = atomicAdd(cnt2, 1u); if (q < CAND2_CAP) cand2[q] = c; }
        }
    }
    __syncthreads();
    unsigned n = lcnt < LCAP2 ? lcnt : LCAP2;
    if (threadIdx.x == 0 && n) gbase = atomicAdd(cnt2, n);
    __syncthreads();
    for (unsigned e = threadIdx.x; e < n; e += blockDim.x) {
        unsigned q = gbase + e;
        if (q < CAND2_CAP) cand2[q] = lc[e];
    }
}

// K10 (1 block): level-2/3 refinement -> exact tau (meta[6]); write the r
// lowest-index exact-tie keepers directly.
__global__ void k_select(unsigned* __restrict__ ws, const uint2* __restrict__ cand2,
                         float* __restrict__ out, const int* __restrict__ kptr) {
    unsigned* meta = ws + META_OFF;
    if (meta[5]) return;
    __shared__ unsigned h[HIST_SIZE];
    __shared__ unsigned ps[1024];
    __shared__ unsigned h3[256];
    __shared__ int ties[TIE_CAP];
    __shared__ unsigned tie_cnt;
    __shared__ unsigned s2_sh, ca2_sh, t3_sh, ca3_sh;
    int t = threadIdx.x;
    unsigned nk = (unsigned)(*kptr) * 1024u;
    unsigned b12 = meta[1];
    unsigned m = nk - meta[2];                     // rank within bucket b12, >=1
    unsigned n2 = meta[7]; if (n2 > CAND2_CAP) n2 = CAND2_CAP;
    for (int i = t; i < HIST_SIZE; i += 1024) {
        unsigned s = 0u;
        #pragma unroll
        for (int r = 0; r < HREP; ++r) s += ws[H2_OFF + r * HIST_SIZE + i];
        h[i] = s;
    }
    if (t < 256) h3[t] = 0u;
    if (t == 0) tie_cnt = 0u;
    __syncthreads();
    unsigned p = h[t*4] + h[t*4+1] + h[t*4+2] + h[t*4+3];
    ps[t] = p;
    __syncthreads();
    for (int st = 1; st < 1024; st <<= 1) {
        unsigned v = (t + st < 1024) ? ps[t + st] : 0u;
        __syncthreads();
        ps[t] += v;
        __syncthreads();
    }
    {
        unsigned S = (t < 1023) ? ps[t + 1] : 0u;
        for (int j = 3; j >= 0; --j) {
            int b = t * 4 + j;
            unsigned Sb = S + h[b];
            if (Sb >= m && S < m) { s2_sh = (unsigned)b; ca2_sh = S; }
            S = Sb;
        }
    }
    __syncthreads();
    unsigned s2 = s2_sh;
    unsigned m2 = m - ca2_sh;                      // rank within sub-bucket, >=1
    for (unsigned i = t; i < n2; i += 1024) {
        uint2 c = cand2[i];
        if (((c.x >> 8) & 0xFFFu) == s2) atomicAdd(&h3[c.x & 0xFFu], 1u);
    }
    __syncthreads();
    if (t < 256) ps[t] = h3[t];
    __syncthreads();
    for (int st = 1; st < 256; st <<= 1) {
        unsigned v = 0u;
        if (t < 256) v = (t + st < 256) ? ps[t + st] : 0u;
        __syncthreads();
        if (t < 256) ps[t] += v;
        __syncthreads();
    }
    if (t < 256) {
        unsigned S3 = (t < 255) ? ps[t + 1] : 0u;
        unsigned Sb = S3 + h3[t];
        if (Sb >= m2 && S3 < m2) { t3_sh = (unsigned)t; ca3_sh = S3; }
    }
    __syncthreads();
    unsigned tau = (b12 << 20) | (s2 << 8) | t3_sh;
    unsigned r = m2 - ca3_sh;                      // exact-tie keepers
    if (t == 0) meta[6] = tau;
    for (unsigned i = t; i < n2; i += 1024) {
        uint2 c = cand2[i];
        if (c.x == tau) {
            unsigned q = atomicAdd(&tie_cnt, 1u);
            if (q < TIE_CAP) ties[q] = (int)c.y;
        }
    }
    __syncthreads();
    unsigned tc = tie_cnt; if (tc > TIE_CAP) tc = TIE_CAP;
    float tv = __uint_as_float(tau);
    for (unsigned e = t; e < tc; e += 1024) {
        int my = ties[e];
        unsigned rank = 0u;
        for (unsigned j = 0; j < tc; ++j) rank += (ties[j] < my) ? 1u : 0u;
        if (rank < r) out[my] = tv;                // keep r lowest-index ties
    }
}

// K11 (512 blocks): sparse scatter of definite keepers (bits > tau), or all if keepall.
__global__ void k_scatter(const unsigned* __restrict__ ws, const uint2* __restrict__ cand,
                          float* __restrict__ out, unsigned cap) {
    const unsigned* meta = ws + META_OFF;
    unsigned keepall = meta[5];
    unsigned tau = meta[6];
    unsigned ncand = meta[0]; if (ncand > cap) ncand = cap;
    unsigned stride = gridDim.x * blockDim.x;
    for (unsigned i = blockIdx.x * blockDim.x + threadIdx.x; i < ncand; i += stride) {
        uint2 c = cand[i];
        if (keepall || c.x > tau) out[c.y] = __uint_as_float(c.x);
    }
}

extern "C" void kernel_launch(void* const* d_in, const int* in_sizes, int n_in,
                              void* d_out, int out_size, void* d_ws, size_t ws_size,
                              hipStream_t stream) {
    const float4* x = (const float4*)d_in[0];
    const int* kptr = (const int*)d_in[1];
    float* out = (float*)d_out;
    unsigned* ws32 = (unsigned*)d_ws;
    uint2* cand2 = (uint2*)(ws32 + CAND2_OFF);
    uint2* cand  = (uint2*)(ws32 + CAND_OFF);

    unsigned cap = CAND_CAP;
    size_t hdr = (size_t)CAND_OFF * 4;
    if (ws_size < hdr + (size_t)CAND_CAP * 8) {
        cap = (ws_size > hdr) ? (unsigned)((ws_size - hdr) / 8) : 0u;
    }

    k_sample<<<SREP, 256, 0, stream>>>(x, ws32);
    k_pick<<<1, 1024, 0, stream>>>(ws32, kptr);
    k_fill<<<2048, 256, 0, stream>>>((float4*)out);
    k_read<<<2048, 256, 0, stream>>>(x, ws32, cand, cap);
    k_histc<<<256, 256, 0, stream>>>(ws32, cand, cap, 0);
    k_scan<<<1, 1024, 0, stream>>>(ws32, kptr, 0);
    k_read_fb<<<2048, 256, 0, stream>>>(x, ws32, cand, cap);    // no-op unless fail
    k_histc<<<256, 256, 0, stream>>>(ws32, cand, cap, 1);       // no-op unless fail
    k_scan<<<1, 1024, 0, stream>>>(ws32, kptr, 1);              // no-op unless fail
    k_filter<<<256, 256, 0, stream>>>(ws32, cand, cand2, cap);
    k_select<<<1, 1024, 0, stream>>>(ws32, cand2, out, kptr);
    k_scatter<<<512, 256, 0, stream>>>(ws32, cand, out, cap);
}

// Round 7
// 114.077 us; speedup vs baseline: 1.2250x; 1.2250x over previous
//
#include <hip/hip_runtime.h>

// BatchTopK: relu(x), keep global top (k*1024) of 1024*24576 fp32, zero rest.
// Exact radix-select on positive-fp32 bit patterns + index-ordered tie-break.
//
// R7: fused single pass again (R6 split regressed), hot loop restructured to
// be branch-free: 12 NT stores issued first, 12 loads clause together,
// branchless 4-bit masks, single rare tail-branch for LDS pushes. R5's
// VGPR=16 showed side-effectful per-element branches serialized the loads.
// Candidate histogram folded into k_main epilogue (packed u16 LDS hist).

#define N_ELEM   25165824            // 1024 * 24576
#define NV       (N_ELEM / 4)        // float4 count = 6291456 = 2048*256*12
#define HIST_SIZE 4096               // top-12-bit buckets
#define HREP     8                   // hist replicas
#define SREP     32                  // sample blocks / private replicas
#define NS       (NV / 64)           // sampled float4 count (1/64)
#define LCAP     1024                // per-block LDS candidate buffer
#define LCAP2    1024
#define TIE_CAP  4096
#define CAND2_CAP 262144
#define CAND_CAP  16777216

typedef float f32x4 __attribute__((ext_vector_type(4)));

// ws layout (uint32 words):
#define H_OFF     0                  // 8 x 4096 main hist (counts bits >= F)
#define H2_OFF    32768              // 8 x 4096 level-2 hist (bits[19:8] in b12)
#define HS_OFF    65536              // 32 x 4096 private sample hists
#define META_OFF  196608             // 16 words
#define CAND2_OFF 196624             // cutoff-bucket candidates, uint2
#define CAND_OFF  720912             // all candidates >= F, uint2 {bits, idx}
// meta: [0]=cand cnt [1]=b12 [2]=c_above [3]=fail [4]=F [5]=keepall
//       [6]=tau [7]=cand2 cnt [8]=cand cnt snapshot (pre-fallback)

// K1 (32 blocks): zero hist+h2+meta; 1/64 sample -> private replica.
__global__ void k_sample(const float4* __restrict__ x, unsigned* __restrict__ ws) {
    __shared__ unsigned lh[HIST_SIZE];
    for (int i = threadIdx.x; i < HIST_SIZE; i += blockDim.x) lh[i] = 0u;
    int gid = blockIdx.x * blockDim.x + threadIdx.x;
    for (int i = gid; i < HS_OFF; i += SREP * 256) ws[i] = 0u;   // zero hist + h2
    if (gid < 16) ws[META_OFF + gid] = 0u;
    __syncthreads();
    for (int s = gid; s < NS; s += SREP * 256) {
        int c = s >> 6, l = s & 63;            // first 64 f4 of each 4096-f4 chunk
        float4 v = x[c * 4096 + l];
        if (v.x > 0.0f) atomicAdd(&lh[__float_as_uint(v.x) >> 20], 1u);
        if (v.y > 0.0f) atomicAdd(&lh[__float_as_uint(v.y) >> 20], 1u);
        if (v.z > 0.0f) atomicAdd(&lh[__float_as_uint(v.z) >> 20], 1u);
        if (v.w > 0.0f) atomicAdd(&lh[__float_as_uint(v.w) >> 20], 1u);
    }
    __syncthreads();
    unsigned* hs = ws + HS_OFF + blockIdx.x * HIST_SIZE;
    for (int i = threadIdx.x; i < HIST_SIZE; i += blockDim.x) hs[i] = lh[i];
}

// K2 (1 block): F = highest bucket with sampled suffix >= 3nk/128
// (expected full count ~1.5*nk, +1 bucket width; 16-sigma safe).
__global__ void k_pick(unsigned* __restrict__ ws, const int* __restrict__ kptr) {
    __shared__ unsigned h[HIST_SIZE];
    __shared__ unsigned ps[1024];
    __shared__ unsigned F_sh;
    int t = threadIdx.x;
    if (t == 0) F_sh = 1u;
    unsigned nk = (unsigned)(*kptr) * 1024u;
    unsigned thr = (3u * nk) / 128u; if (thr < 1u) thr = 1u;
    for (int i = t; i < HIST_SIZE; i += 1024) {
        unsigned s = 0u;
        #pragma unroll
        for (int r = 0; r < SREP; ++r) s += ws[HS_OFF + r * HIST_SIZE + i];
        h[i] = s;
    }
    __syncthreads();
    unsigned p = h[t*4] + h[t*4+1] + h[t*4+2] + h[t*4+3];
    ps[t] = p;
    __syncthreads();
    for (int st = 1; st < 1024; st <<= 1) {
        unsigned v = (t + st < 1024) ? ps[t + st] : 0u;
        __syncthreads();
        ps[t] += v;
        __syncthreads();
    }
    unsigned S = (t < 1023) ? ps[t + 1] : 0u;
    for (int j = 3; j >= 0; --j) {
        int b = t * 4 + j;
        unsigned Sb = S + h[b];
        if (Sb >= thr && S < thr) F_sh = ((unsigned)b) << 20;
        S = Sb;
    }
    __syncthreads();
    if (t == 0) ws[META_OFF + 4] = F_sh;
}

__device__ __forceinline__ unsigned mask4(float4 v, unsigned F) {
    unsigned m = 0u;
    m |= (__float_as_uint(fmaxf(v.x, 0.f)) >= F) ? 1u : 0u;
    m |= (__float_as_uint(fmaxf(v.y, 0.f)) >= F) ? 2u : 0u;
    m |= (__float_as_uint(fmaxf(v.z, 0.f)) >= F) ? 4u : 0u;
    m |= (__float_as_uint(fmaxf(v.w, 0.f)) >= F) ? 8u : 0u;
    return m;
}

// Rare path: push masked elements of one float4. m!=0 guaranteed positive vals.
__device__ __forceinline__ void push4(float4 v, unsigned m, unsigned base,
                                      unsigned* lcnt, uint2* lc,
                                      unsigned* gcnt, uint2* cand, unsigned cap,
                                      unsigned* gh) {
    while (m) {
        unsigned c = (unsigned)__ffs(m) - 1u;
        m &= m - 1u;
        float a = (c == 0u) ? v.x : (c == 1u) ? v.y : (c == 2u) ? v.z : v.w;
        unsigned b = __float_as_uint(a);           // a > 0 here, bits == relu bits
        unsigned p = atomicAdd(lcnt, 1u);
        if (p < LCAP) lc[p] = make_uint2(b, base + c);
        else {                                      // spill (~never): keep exact
            unsigned q = atomicAdd(gcnt, 1u);
            if (q < cap) { cand[q] = make_uint2(b, base + c); atomicAdd(&gh[b >> 20], 1u); }
        }
    }
}

// K3 (2048 blocks x 256, one shot): fused pass. Stores-first, loads clause,
// branchless masks, one rare tail branch. Epilogue: block-local candidate
// histogram (packed u16) + single global-atomic flush.
__global__ __launch_bounds__(256) void k_main(const float4* __restrict__ x,
                                              float4* __restrict__ out,
                                              unsigned* __restrict__ ws,
                                              uint2* __restrict__ cand, unsigned cap) {
    __shared__ uint2 lc[LCAP];                      // 8 KB
    __shared__ unsigned lhp[HIST_SIZE / 2];         // 8 KB packed u16 pairs
    __shared__ unsigned lcnt, gbase;
    if (threadIdx.x == 0) lcnt = 0u;
    __syncthreads();
    unsigned* meta = ws + META_OFF;
    unsigned F = meta[4];
    unsigned* gcnt = &meta[0];
    unsigned* gh = ws + H_OFF + (blockIdx.x & (HREP - 1)) * HIST_SIZE;
    const f32x4 z = {0.f, 0.f, 0.f, 0.f};
    int tid = blockIdx.x * 256 + threadIdx.x;
    const int stride = 2048 * 256;

    // 12 independent NT zero-stores (no input dependency).
    #pragma unroll
    for (int j = 0; j < 12; ++j)
        __builtin_nontemporal_store(z, (f32x4*)&out[tid + j * stride]);

    // 12 loads -> named regs (clause together), then branchless masks.
#define LOADV(k) float4 v##k = x[tid + (k) * stride];
    LOADV(0) LOADV(1) LOADV(2) LOADV(3) LOADV(4) LOADV(5)
    LOADV(6) LOADV(7) LOADV(8) LOADV(9) LOADV(10) LOADV(11)
#undef LOADV
#define MASKV(k) unsigned m##k = mask4(v##k, F);
    MASKV(0) MASKV(1) MASKV(2) MASKV(3) MASKV(4) MASKV(5)
    MASKV(6) MASKV(7) MASKV(8) MASKV(9) MASKV(10) MASKV(11)
#undef MASKV
    if (m0|m1|m2|m3|m4|m5|m6|m7|m8|m9|m10|m11) {
#define PUSHV(k) if (m##k) push4(v##k, m##k, (unsigned)(tid + (k) * stride) * 4u, \
                                 &lcnt, lc, gcnt, cand, cap, gh);
        PUSHV(0) PUSHV(1) PUSHV(2) PUSHV(3) PUSHV(4) PUSHV(5)
        PUSHV(6) PUSHV(7) PUSHV(8) PUSHV(9) PUSHV(10) PUSHV(11)
#undef PUSHV
    }

    // Epilogue: histogram own candidates (u16-packed; counts <= LCAP so no
    // overflow into the partner half), then one global atomic for slots.
    __syncthreads();
    for (int i = threadIdx.x; i < HIST_SIZE / 2; i += 256) lhp[i] = 0u;
    __syncthreads();
    unsigned n = lcnt < LCAP ? lcnt : LCAP;
    for (unsigned e = threadIdx.x; e < n; e += 256) {
        unsigned b12 = lc[e].x >> 20;
        atomicAdd(&lhp[b12 >> 1], 1u << ((b12 & 1u) * 16u));
    }
    __syncthreads();
    if (threadIdx.x == 0 && n) gbase = atomicAdd(gcnt, n);
    __syncthreads();
    for (unsigned e = threadIdx.x; e < n; e += 256) {
        unsigned q = gbase + e;
        if (q < cap) cand[q] = lc[e];
    }
    for (int i = threadIdx.x; i < HIST_SIZE / 2; i += 256) {
        unsigned w = lhp[i];
        if (w & 0xFFFFu)  atomicAdd(&gh[i * 2],     w & 0xFFFFu);
        if (w >> 16)      atomicAdd(&gh[i * 2 + 1], w >> 16);
    }
}

// K5 (guarded on fail): complement pass (0 < bits < F) appends candidates +
// histogram counts, restoring full-histogram exactness.
__global__ void k_main_fb(const float4* __restrict__ x, unsigned* __restrict__ ws,
                          uint2* __restrict__ cand, unsigned cap) {
    unsigned* meta = ws + META_OFF;
    if (meta[3] == 0u) return;
    __shared__ uint2 lc[LCAP];
    __shared__ unsigned lhp[HIST_SIZE / 2];
    __shared__ unsigned lcnt, gbase;
    if (threadIdx.x == 0) lcnt = 0u;
    __syncthreads();
    unsigned F = meta[4];
    unsigned* gcnt = &meta[0];
    unsigned* gh = ws + H_OFF + (blockIdx.x & (HREP - 1)) * HIST_SIZE;
    int stride = gridDim.x * blockDim.x;
    for (int i = blockIdx.x * blockDim.x + threadIdx.x; i < NV; i += stride) {
        float4 v = x[i];
        unsigned base = (unsigned)i * 4u;
        unsigned b;
        b = __float_as_uint(fmaxf(v.x, 0.f)); if (b >= 1u && b < F) push4(make_float4(v.x,0,0,0), 1u, base + 0u, &lcnt, lc, gcnt, cand, cap, gh);
        b = __float_as_uint(fmaxf(v.y, 0.f)); if (b >= 1u && b < F) push4(make_float4(v.y,0,0,0), 1u, base + 1u, &lcnt, lc, gcnt, cand, cap, gh);
        b = __float_as_uint(fmaxf(v.z, 0.f)); if (b >= 1u && b < F) push4(make_float4(v.z,0,0,0), 1u, base + 2u, &lcnt, lc, gcnt, cand, cap, gh);
        b = __float_as_uint(fmaxf(v.w, 0.f)); if (b >= 1u && b < F) push4(make_float4(v.w,0,0,0), 1u, base + 3u, &lcnt, lc, gcnt, cand, cap, gh);
    }
    __syncthreads();
    for (int i = threadIdx.x; i < HIST_SIZE / 2; i += blockDim.x) lhp[i] = 0u;
    __syncthreads();
    unsigned n = lcnt < LCAP ? lcnt : LCAP;
    for (unsigned e = threadIdx.x; e < n; e += blockDim.x) {
        unsigned b12 = lc[e].x >> 20;
        atomicAdd(&lhp[b12 >> 1], 1u << ((b12 & 1u) * 16u));
    }
    __syncthreads();
    if (threadIdx.x == 0 && n) gbase = atomicAdd(gcnt, n);
    __syncthreads();
    for (unsigned e = threadIdx.x; e < n; e += blockDim.x) {
        unsigned q = gbase + e;
        if (q < cap) cand[q] = lc[e];
    }
    for (int i = threadIdx.x; i < HIST_SIZE / 2; i += blockDim.x) {
        unsigned w = lhp[i];
        if (w & 0xFFFFu)  atomicAdd(&gh[i * 2],     w & 0xFFFFu);
        if (w >> 16)      atomicAdd(&gh[i * 2 + 1], w >> 16);
    }
}

// K4/K6 (1 block): suffix-scan replica-summed hist -> b12, c_above | fail | keepall.
__global__ void k_scan(unsigned* __restrict__ ws, const int* __restrict__ kptr, int is_fb) {
    unsigned* meta = ws + META_OFF;
    if (is_fb && meta[3] == 0u) return;
    __shared__ unsigned h[HIST_SIZE];
    __shared__ unsigned ps[1024];
    int t = threadIdx.x;
    unsigned nk = (unsigned)(*kptr) * 1024u;
    for (int i = t; i < HIST_SIZE; i += 1024) {
        unsigned s = 0u;
        #pragma unroll
        for (int r = 0; r < HREP; ++r) s += ws[H_OFF + r * HIST_SIZE + i];
        h[i] = s;
    }
    __syncthreads();
    unsigned p = h[t*4] + h[t*4+1] + h[t*4+2] + h[t*4+3];
    ps[t] = p;
    __syncthreads();
    for (int st = 1; st < 1024; st <<= 1) {
        unsigned v = (t + st < 1024) ? ps[t + st] : 0u;
        __syncthreads();
        ps[t] += v;
        __syncthreads();
    }
    unsigned total = ps[0];
    if (total < nk) {
        if (t == 0) {
            if (!is_fb) { meta[3] = 1u; meta[8] = meta[0]; }   // snapshot count
            else meta[5] = 1u;                                  // keep all positives
        }
        return;
    }
    unsigned S = (t < 1023) ? ps[t + 1] : 0u;
    for (int j = 3; j >= 0; --j) {
        int b = t * 4 + j;
        unsigned Sb = S + h[b];
        if (Sb >= nk && S < nk) { meta[1] = (unsigned)b; meta[2] = S; }
        S = Sb;
    }
}

// K7 (256 blocks): extract cutoff-bucket cands -> cand2, level-2 hist replicas.
__global__ void k_filter(unsigned* __restrict__ ws, const uint2* __restrict__ cand,
                         uint2* __restrict__ cand2, unsigned cap) {
    unsigned* meta = ws + META_OFF;
    if (meta[5]) return;
    __shared__ uint2 lc[LCAP2];
    __shared__ unsigned lcnt, gbase;
    if (threadIdx.x == 0) lcnt = 0u;
    __syncthreads();
    unsigned ncand = meta[0]; if (ncand > cap) ncand = cap;
    unsigned b12 = meta[1];
    unsigned* h2 = ws + H2_OFF + (blockIdx.x & (HREP - 1)) * HIST_SIZE;
    unsigned* cnt2 = &meta[7];
    unsigned stride = gridDim.x * blockDim.x;
    for (unsigned i = blockIdx.x * blockDim.x + threadIdx.x; i < ncand; i += stride) {
        uint2 c = cand[i];
        if ((c.x >> 20) == b12) {
            atomicAdd(&h2[(c.x >> 8) & 0xFFFu], 1u);
            unsigned p = atomicAdd(&lcnt, 1u);
            if (p < LCAP2) lc[p] = c;
            else { unsigned q = atomicAdd(cnt2, 1u); if (q < CAND2_CAP) cand2[q] = c; }
        }
    }
    __syncthreads();
    unsigned n = lcnt < LCAP2 ? lcnt : LCAP2;
    if (threadIdx.x == 0 && n) gbase = atomicAdd(cnt2, n);
    __syncthreads();
    for (unsigned e = threadIdx.x; e < n; e += blockDim.x) {
        unsigned q = gbase + e;
        if (q < CAND2_CAP) cand2[q] = lc[e];
    }
}

// K8 (1 block): level-2/3 refinement -> exact tau (meta[6]); write the r
// lowest-index exact-tie keepers directly.
__global__ void k_select(unsigned* __restrict__ ws, const uint2* __restrict__ cand2,
                         float* __restrict__ out, const int* __restrict__ kptr) {
    unsigned* meta = ws + META_OFF;
    if (meta[5]) return;
    __shared__ unsigned h[HIST_SIZE];
    __shared__ unsigned ps[1024];
    __shared__ unsigned h3[256];
    __shared__ int ties[TIE_CAP];
    __shared__ unsigned tie_cnt;
    __shared__ unsigned s2_sh, ca2_sh, t3_sh, ca3_sh;
    int t = threadIdx.x;
    unsigned nk = (unsigned)(*kptr) * 1024u;
    unsigned b12 = meta[1];
    unsigned m = nk - meta[2];                     // rank within bucket b12, >=1
    unsigned n2 = meta[7]; if (n2 > CAND2_CAP) n2 = CAND2_CAP;
    for (int i = t; i < HIST_SIZE; i += 1024) {
        unsigned s = 0u;
        #pragma unroll
        for (int r = 0; r < HREP; ++r) s += ws[H2_OFF + r * HIST_SIZE + i];
        h[i] = s;
    }
    if (t < 256) h3[t] = 0u;
    if (t == 0) tie_cnt = 0u;
    __syncthreads();
    unsigned p = h[t*4] + h[t*4+1] + h[t*4+2] + h[t*4+3];
    ps[t] = p;
    __syncthreads();
    for (int st = 1; st < 1024; st <<= 1) {
        unsigned v = (t + st < 1024) ? ps[t + st] : 0u;
        __syncthreads();
        ps[t] += v;
        __syncthreads();
    }
    {
        unsigned S = (t < 1023) ? ps[t + 1] : 0u;
        for (int j = 3; j >= 0; --j) {
            int b = t * 4 + j;
            unsigned Sb = S + h[b];
            if (Sb >= m && S < m) { s2_sh = (unsigned)b; ca2_sh = S; }
            S = Sb;
        }
    }
    __syncthreads();
    unsigned s2 = s2_sh;
    unsigned m2 = m - ca2_sh;                      // rank within sub-bucket, >=1
    for (unsigned i = t; i < n2; i += 1024) {
        uint2 c = cand2[i];
        if (((c.x >> 8) & 0xFFFu) == s2) atomicAdd(&h3[c.x & 0xFFu], 1u);
    }
    __syncthreads();
    if (t < 256) ps[t] = h3[t];
    __syncthreads();
    for (int st = 1; st < 256; st <<= 1) {
        unsigned v = 0u;
        if (t < 256) v = (t + st < 256) ? ps[t + st] : 0u;
        __syncthreads();
        if (t < 256) ps[t] += v;
        __syncthreads();
    }
    if (t < 256) {
        unsigned S3 = (t < 255) ? ps[t + 1] : 0u;
        unsigned Sb = S3 + h3[t];
        if (Sb >= m2 && S3 < m2) { t3_sh = (unsigned)t; ca3_sh = S3; }
    }
    __syncthreads();
    unsigned tau = (b12 << 20) | (s2 << 8) | t3_sh;
    unsigned r = m2 - ca3_sh;                      // exact-tie keepers
    if (t == 0) meta[6] = tau;
    for (unsigned i = t; i < n2; i += 1024) {
        uint2 c = cand2[i];
        if (c.x == tau) {
            unsigned q = atomicAdd(&tie_cnt, 1u);
            if (q < TIE_CAP) ties[q] = (int)c.y;
        }
    }
    __syncthreads();
    unsigned tc = tie_cnt; if (tc > TIE_CAP) tc = TIE_CAP;
    float tv = __uint_as_float(tau);
    for (unsigned e = t; e < tc; e += 1024) {
        int my = ties[e];
        unsigned rank = 0u;
        for (unsigned j = 0; j < tc; ++j) rank += (ties[j] < my) ? 1u : 0u;
        if (rank < r) out[my] = tv;                // keep r lowest-index ties
    }
}

// K9 (512 blocks): sparse scatter of definite keepers (bits > tau), or all if keepall.
__global__ void k_scatter(const unsigned* __restrict__ ws, const uint2* __restrict__ cand,
                          float* __restrict__ out, unsigned cap) {
    const unsigned* meta = ws + META_OFF;
    unsigned keepall = meta[5];
    unsigned tau = meta[6];
    unsigned ncand = meta[0]; if (ncand > cap) ncand = cap;
    unsigned stride = gridDim.x * blockDim.x;
    for (unsigned i = blockIdx.x * blockDim.x + threadIdx.x; i < ncand; i += stride) {
        uint2 c = cand[i];
        if (keepall || c.x > tau) out[c.y] = __uint_as_float(c.x);
    }
}

extern "C" void kernel_launch(void* const* d_in, const int* in_sizes, int n_in,
                              void* d_out, int out_size, void* d_ws, size_t ws_size,
                              hipStream_t stream) {
    const float4* x = (const float4*)d_in[0];
    const int* kptr = (const int*)d_in[1];
    float* out = (float*)d_out;
    unsigned* ws32 = (unsigned*)d_ws;
    uint2* cand2 = (uint2*)(ws32 + CAND2_OFF);
    uint2* cand  = (uint2*)(ws32 + CAND_OFF);

    unsigned cap = CAND_CAP;
    size_t hdr = (size_t)CAND_OFF * 4;
    if (ws_size < hdr + (size_t)CAND_CAP * 8) {
        cap = (ws_size > hdr) ? (unsigned)((ws_size - hdr) / 8) : 0u;
    }

    k_sample<<<SREP, 256, 0, stream>>>(x, ws32);
    k_pick<<<1, 1024, 0, stream>>>(ws32, kptr);
    k_main<<<2048, 256, 0, stream>>>(x, (float4*)out, ws32, cand, cap);
    k_scan<<<1, 1024, 0, stream>>>(ws32, kptr, 0);
    k_main_fb<<<2048, 256, 0, stream>>>(x, ws32, cand, cap);    // no-op unless fail
    k_scan<<<1, 1024, 0, stream>>>(ws32, kptr, 1);              // no-op unless fail
    k_filter<<<256, 256, 0, stream>>>(ws32, cand, cand2, cap);
    k_select<<<1, 1024, 0, stream>>>(ws32, cand2, out, kptr);
    k_scatter<<<512, 256, 0, stream>>>(ws32, cand, out, cap);
}